// Round 4
// baseline (146.655 us; speedup 1.0000x reference)
//
#include <hip/hip_runtime.h>
#include <math.h>

#define CHANNEL 8
#define KDIM 16
#define DFULL 128
#define MNBR 32
#define ROUT_IT 3
#define TM1 64

typedef __attribute__((ext_vector_type(4))) float f32x4;
typedef __attribute__((ext_vector_type(8))) short short8;
typedef __attribute__((ext_vector_type(8))) _Float16 half8;
typedef __attribute__((ext_vector_type(2))) _Float16 half2v;

// f32 pair -> packed f16 dword (v_cvt_pkrtz_f16_f32, 1 instr)
__device__ inline unsigned pk16(float a, float b) {
  auto r = __builtin_amdgcn_cvt_pkrtz(a, b);
  return __builtin_bit_cast(unsigned, r);
}
// packed-f16 dot2 with f32 accumulate: v_dot2_f32_f16 (1 instr, no unpack)
__device__ inline float fdot2(unsigned a, unsigned b, float c) {
  return __builtin_amdgcn_fdot2(__builtin_bit_cast(half2v, a),
                                __builtin_bit_cast(half2v, b), c, false);
}
__device__ inline float h2f_lo(unsigned w) {
  union { ushort u; _Float16 h; } v; v.u = (ushort)(w & 0xffffu); return (float)v.h;
}
__device__ inline float h2f_hi(unsigned w) {
  union { ushort u; _Float16 h; } v; v.u = (ushort)(w >> 16); return (float)v.h;
}
// packed f16 helpers (v_pk_fma_f16 / v_pk_add_f16 / v_pk_mul_f16)
__device__ inline half2v h2(unsigned u) { return __builtin_bit_cast(half2v, u); }
__device__ inline unsigned unh(half2v h) { return __builtin_bit_cast(unsigned, h); }
__device__ inline unsigned pkfma16(unsigned a, unsigned b, unsigned c) {
  return unh(__builtin_elementwise_fma(h2(a), h2(b), h2(c)));
}
// DPP reduction step: x + dpp_move<C>(x). 0xB1=quad_perm xor1, 0x4E=quad_perm
// xor2, 0x141=row_half_mirror (xor4 once lower 2 bits uniform).
template <int C>
__device__ inline float dppadd(float x) {
  int m = __builtin_amdgcn_update_dpp(0, __builtin_bit_cast(int, x), C, 0xF, 0xF, true);
  return x + __builtin_bit_cast(float, m);
}

union H8 { unsigned u[4]; short8 v; };
__device__ inline short8 pack8h(float4 a, float4 b) {  // 8 f32 -> 8 f16 (RTZ)
  H8 r;
  r.u[0] = pk16(a.x, a.y); r.u[1] = pk16(a.z, a.w);
  r.u[2] = pk16(b.x, b.y); r.u[3] = pk16(b.z, b.w);
  return r.v;
}

// ---------------------------------------------------------------------------
// K0: pack W (128x128 f32) into f16 MFMA B-fragment order. (unchanged)
// ---------------------------------------------------------------------------
__global__ __launch_bounds__(256) void wpack_kernel(const float* __restrict__ W,
                                                    ushort* __restrict__ wpk) {
  int task = blockIdx.x * 256 + threadIdx.x;  // 2048 = 32 frags x 64 lanes
  if (task >= 2048) return;
  int f = task >> 6, l = task & 63;
  int kk = f >> 3, j = f & 7, L = l & 15, H = l >> 4;
  const float* src = W + (size_t)(j * 16 + L) * 128 + kk * 32 + H * 8;
  float4 a = *(const float4*)src;
  float4 b = *(const float4*)(src + 4);
  *(short8*)(wpk + (size_t)task * 8) = pack8h(a, b);
}

// ---------------------------------------------------------------------------
// K1: z16[r] = f16(normalize_per_capsule(relu(x @ W^T + b))), row n = 0.
// (unchanged — bounded < 54 µs by top-5 absence; routing is this round's
// single variable)
// ---------------------------------------------------------------------------
__global__ __launch_bounds__(256) void fc_mfma_kernel(
    const float* __restrict__ x, const ushort* __restrict__ wpk,
    const float* __restrict__ bias, ushort* __restrict__ z16, int n) {
  __shared__ __align__(16) float smem[TM1 * 132];  // 33792 B >= 32768 B wpk stage

  const int t = threadIdx.x, lane = t & 63, w = t >> 6;

  {
    const uint4* gw = (const uint4*)wpk;
    uint4* lw = (uint4*)smem;
#pragma unroll
    for (int i = 0; i < 8; ++i) lw[i * 256 + t] = gw[i * 256 + t];
  }

  const int L = lane & 15, H = lane >> 4;
  const int r0 = blockIdx.x * TM1;
  const int row = r0 + w * 16 + L;
  const bool ok = row < n;
  const float4 z4 = make_float4(0.f, 0.f, 0.f, 0.f);

  const float* xr = x + (size_t)row * DFULL + H * 8;
  short8 af[4];
#pragma unroll
  for (int kk = 0; kk < 4; ++kk) {
    float4 xa = ok ? *(const float4*)(xr + kk * 32) : z4;
    float4 xb = ok ? *(const float4*)(xr + kk * 32 + 4) : z4;
    af[kk] = pack8h(xa, xb);
  }

  f32x4 acc[8];
#pragma unroll
  for (int j = 0; j < 8; ++j) {
    float bv = bias[j * 16 + L];
    acc[j] = (f32x4){bv, bv, bv, bv};
  }
  __syncthreads();  // wpk staged
  const short8* wf = (const short8*)smem;
#pragma unroll
  for (int j = 0; j < 8; ++j)
#pragma unroll
    for (int kk = 0; kk < 4; ++kk) {
      short8 bfr = wf[(kk * 8 + j) * 64 + lane];
      acc[j] = __builtin_amdgcn_mfma_f32_16x16x32_f16(
          __builtin_bit_cast(half8, af[kk]), __builtin_bit_cast(half8, bfr),
          acc[j], 0, 0, 0);
    }
  __syncthreads();  // all waves done reading wpk LDS; reuse as ys

  float* ys = smem;
  const int lr = w * 16 + H * 4;
#pragma unroll
  for (int j = 0; j < 8; ++j)
#pragma unroll
    for (int r = 0; r < 4; ++r)
      ys[(lr + r) * 132 + j * 16 + L] = fmaxf(acc[j][r], 0.f);
  __syncthreads();

#pragma unroll
  for (int pass = 0; pass < 2; ++pass) {
    int task = t + pass * 256;
    int rr = task >> 3, cc = task & 7;
    const float4* yr = (const float4*)(ys + rr * 132 + cc * 16);
    float4 a = yr[0], b = yr[1], c4 = yr[2], d4 = yr[3];
    float ss = a.x * a.x;
    ss = fmaf(a.y, a.y, ss); ss = fmaf(a.z, a.z, ss); ss = fmaf(a.w, a.w, ss);
    ss = fmaf(b.x, b.x, ss); ss = fmaf(b.y, b.y, ss); ss = fmaf(b.z, b.z, ss);
    ss = fmaf(b.w, b.w, ss); ss = fmaf(c4.x, c4.x, ss); ss = fmaf(c4.y, c4.y, ss);
    ss = fmaf(c4.z, c4.z, ss); ss = fmaf(c4.w, c4.w, ss); ss = fmaf(d4.x, d4.x, ss);
    ss = fmaf(d4.y, d4.y, ss); ss = fmaf(d4.z, d4.z, ss); ss = fmaf(d4.w, d4.w, ss);
    float sc = 1.f / fmaxf(sqrtf(ss), 1e-12f);
    int grow = r0 + rr;
    if (grow < n) {
      uint4 o0, o1;
      o0.x = pk16(a.x * sc, a.y * sc);  o0.y = pk16(a.z * sc, a.w * sc);
      o0.z = pk16(b.x * sc, b.y * sc);  o0.w = pk16(b.z * sc, b.w * sc);
      o1.x = pk16(c4.x * sc, c4.y * sc); o1.y = pk16(c4.z * sc, c4.w * sc);
      o1.z = pk16(d4.x * sc, d4.y * sc); o1.w = pk16(d4.z * sc, d4.w * sc);
      uint4* dst = (uint4*)(z16 + (size_t)grow * DFULL + cc * 16);
      dst[0] = o0; dst[1] = o1;
    } else if (grow == n) {  // pad row = zeros
      uint4 zz = {0u, 0u, 0u, 0u};
      uint4* dst = (uint4*)(z16 + (size_t)grow * DFULL + cc * 16);
      dst[0] = zz; dst[1] = zz;
    }
  }
}

// ---------------------------------------------------------------------------
// K2: routing — register-resident, zero LDS arrays, zero barriers.
// Round-4 deltas: (1) residual folded into accumulator seed: acc starts at
// x/8 (exact f16 exponent shift; all 8 q-lanes hold the same x slice, so the
// q-butterfly sums 8*(x/8) = x) — removes the mul + post-butterfly add per
// dword per iter; (2) xpk freed after init; (3) launch_bounds(256,6) caps
// VGPR at 84 -> 6 waves/SIMD to hide swizzle/gather latency.
// ---------------------------------------------------------------------------
__global__ __launch_bounds__(256, 6) void routing_kernel(
    const ushort* __restrict__ z16, const int* __restrict__ nid,
    float* __restrict__ out, int n) {
  const int t = threadIdx.x;
  const int node = blockIdx.x * 4 + (t >> 6);
  if (node >= n) return;
  const int lane = t & 63;
  const int q = lane >> 3, c = lane & 7;

  // ---- load this lane's 4 neighbor-row channel slices (16 f16 = 32B each).
  int4 ids = *(const int4*)(nid + node * MNBR + 4 * q);
  const uint4* g0 = (const uint4*)(z16 + (size_t)ids.x * DFULL + c * KDIM);
  const uint4* g1 = (const uint4*)(z16 + (size_t)ids.y * DFULL + c * KDIM);
  const uint4* g2 = (const uint4*)(z16 + (size_t)ids.z * DFULL + c * KDIM);
  const uint4* g3 = (const uint4*)(z16 + (size_t)ids.w * DFULL + c * KDIM);
  uint4 R0a = g0[0], R0b = g0[1];
  uint4 R1a = g1[0], R1b = g1[1];
  uint4 R2a = g2[0], R2b = g2[1];
  uint4 R3a = g3[0], R3b = g3[1];
  unsigned r0[8] = {R0a.x, R0a.y, R0a.z, R0a.w, R0b.x, R0b.y, R0b.z, R0b.w};
  unsigned r1[8] = {R1a.x, R1a.y, R1a.z, R1a.w, R1b.x, R1b.y, R1b.z, R1b.w};
  unsigned r2[8] = {R2a.x, R2a.y, R2a.z, R2a.w, R2b.x, R2b.y, R2b.z, R2b.w};
  unsigned r3[8] = {R3a.x, R3a.y, R3a.z, R3a.w, R3b.x, R3b.y, R3b.z, R3b.w};

  // own row, channel c slice (identical across the 8 q-lanes)
  const uint4* xp = (const uint4*)(z16 + (size_t)node * DFULL + c * KDIM);
  uint4 X0 = xp[0], X1 = xp[1];
  const unsigned EIGHTH = 0x30003000u;  // packed f16 (0.125, 0.125)
  unsigned upk[8], xk8[8];
  {
    unsigned xpk[8] = {X0.x, X0.y, X0.z, X0.w, X1.x, X1.y, X1.z, X1.w};
#pragma unroll
    for (int i = 0; i < 8; ++i) {
      upk[i] = xpk[i];
      xk8[i] = unh(h2(xpk[i]) * h2(EIGHTH));  // exact (exponent shift)
    }
  }

#pragma unroll
  for (int it = 0; it < ROUT_IT; ++it) {
    // ---- p-phase: agreement dots for this lane's 4 rows (TAU = 1)
    float A0 = 0.f, A1 = 0.f, A2 = 0.f, A3 = 0.f;
#pragma unroll
    for (int i = 0; i < 8; ++i) {
      A0 = fdot2(r0[i], upk[i], A0);
      A1 = fdot2(r1[i], upk[i], A1);
      A2 = fdot2(r2[i], upk[i], A2);
      A3 = fdot2(r3[i], upk[i], A3);
    }
    float e0 = __expf(A0), e1 = __expf(A1), e2 = __expf(A2), e3 = __expf(A3);
    // softmax denominator over the 8 contiguous c-lanes (same q) via DPP
    float D0 = dppadd<0x141>(dppadd<0x4E>(dppadd<0xB1>(e0)));
    float D1 = dppadd<0x141>(dppadd<0x4E>(dppadd<0xB1>(e1)));
    float D2 = dppadd<0x141>(dppadd<0x4E>(dppadd<0xB1>(e2)));
    float D3 = dppadd<0x141>(dppadd<0x4E>(dppadd<0xB1>(e3)));
    unsigned sp0, sp1, sp2, sp3;
    {
      float s0 = e0 * __builtin_amdgcn_rcpf(D0);
      float s1 = e1 * __builtin_amdgcn_rcpf(D1);
      float s2 = e2 * __builtin_amdgcn_rcpf(D2);
      float s3 = e3 * __builtin_amdgcn_rcpf(D3);
      sp0 = pk16(s0, s0); sp1 = pk16(s1, s1);
      sp2 = pk16(s2, s2); sp3 = pk16(s3, s3);
    }
    // ---- u-phase: weighted sum of own 4 rows, seeded with x/8 (residual
    // distributes across the 8-lane butterfly: 8 * x/8 = x)
    unsigned acc[8];
#pragma unroll
    for (int i = 0; i < 8; ++i) {
      unsigned a = pkfma16(r3[i], sp3, xk8[i]);
      a = pkfma16(r2[i], sp2, a);
      a = pkfma16(r1[i], sp1, a);
      acc[i] = pkfma16(r0[i], sp0, a);
    }
    // ---- butterfly sum over the 8 q-lanes (lane bits 3,4,5)
#pragma unroll
    for (int i = 0; i < 8; ++i) {
      int v = __builtin_amdgcn_ds_swizzle((int)acc[i], 0x201F);  // lane^8
      acc[i] = unh(h2(acc[i]) + h2((unsigned)v));
    }
#pragma unroll
    for (int i = 0; i < 8; ++i) {
      int v = __builtin_amdgcn_ds_swizzle((int)acc[i], 0x401F);  // lane^16
      acc[i] = unh(h2(acc[i]) + h2((unsigned)v));
    }
#pragma unroll
    for (int i = 0; i < 8; ++i) {
      int v = __shfl_xor((int)acc[i], 32);                        // lane^32
      acc[i] = unh(h2(acc[i]) + h2((unsigned)v));
    }

    if (it == ROUT_IT - 1) {
      // lane writes k = 2q, 2q+1 (dword q of acc): static 8->1 select tree
      unsigned a0 = (q & 1) ? acc[1] : acc[0];
      unsigned a1 = (q & 1) ? acc[3] : acc[2];
      unsigned a2 = (q & 1) ? acc[5] : acc[4];
      unsigned a3 = (q & 1) ? acc[7] : acc[6];
      unsigned b0 = (q & 2) ? a1 : a0;
      unsigned b1 = (q & 2) ? a3 : a2;
      unsigned sel = (q & 4) ? b1 : b0;
      float2 st; st.x = h2f_lo(sel); st.y = h2f_hi(sel);
      *(float2*)(out + (size_t)node * DFULL + c * KDIM + 2 * q) = st;
    } else {
      // capsule normalize (all 16 k are local): 8 fdot2 + rsq
      float ss = 0.f;
#pragma unroll
      for (int i = 0; i < 8; ++i) ss = fdot2(acc[i], acc[i], ss);
      float sc = __builtin_amdgcn_rsqf(fmaxf(ss, 1e-24f));
      unsigned scp = pk16(sc, sc);
#pragma unroll
      for (int i = 0; i < 8; ++i) upk[i] = unh(h2(acc[i]) * h2(scp));
    }
  }
}

// ---------------------------------------------------------------------------
extern "C" void kernel_launch(void* const* d_in, const int* in_sizes, int n_in,
                              void* d_out, int out_size, void* d_ws, size_t ws_size,
                              hipStream_t stream) {
  const float* x = (const float*)d_in[0];
  const float* W = (const float*)d_in[1];
  const float* b = (const float*)d_in[2];
  const int* nid = (const int*)d_in[3];
  float* out = (float*)d_out;

  int n = in_sizes[0] / DFULL;            // 50000
  int g1 = (n + 1 + TM1 - 1) / TM1;       // 782 (covers rows 0..n)
  size_t zrows = (size_t)g1 * TM1;        // 50048

  ushort* z16 = (ushort*)d_ws;                   // zrows x 128 f16 table
  ushort* wpk = (ushort*)d_ws + zrows * DFULL;   // 2048 x 8 f16 W fragments

  wpack_kernel<<<8, 256, 0, stream>>>(W, wpk);
  fc_mfma_kernel<<<g1, 256, 0, stream>>>(x, wpk, b, z16, n);
  routing_kernel<<<(n + 3) / 4, 256, 0, stream>>>(z16, nid, out, n);
}